// Round 15
// baseline (269.665 us; speedup 1.0000x reference)
//
#include <hip/hip_runtime.h>

typedef unsigned short u16;
typedef unsigned int   u32;
typedef short bf16x8 __attribute__((ext_vector_type(8)));
typedef float f32x4  __attribute__((ext_vector_type(4)));
typedef float f32x16 __attribute__((ext_vector_type(16)));
typedef float f4     __attribute__((ext_vector_type(4)));
typedef u16   u16x4  __attribute__((ext_vector_type(4)));
typedef u16   u16x8  __attribute__((ext_vector_type(8)));
typedef u32   u32x2  __attribute__((ext_vector_type(2)));

__device__ __forceinline__ u16 f2bf(float x) {
  u32 u = __float_as_uint(x);
  u += 0x7fff + ((u >> 16) & 1);
  return (u16)(u >> 16);
}
__device__ __forceinline__ float bf2f(u16 h) {
  return __uint_as_float(((u32)h) << 16);
}
__device__ __forceinline__ void gload16(const void* g, void* l) {
  __builtin_amdgcn_global_load_lds((const __attribute__((address_space(1))) u32*)g,
                                   (__attribute__((address_space(3))) u32*)l, 16, 0, 0);
}
__device__ __forceinline__ f32x4 mfma16(bf16x8 a, bf16x8 b, f32x4 c) {
  return __builtin_amdgcn_mfma_f32_16x16x32_bf16(a, b, c, 0, 0, 0);
}
__device__ __forceinline__ f32x16 mfma32(bf16x8 a, bf16x8 b, f32x16 c) {
  return __builtin_amdgcn_mfma_f32_32x32x16_bf16(a, b, c, 0, 0, 0);
}

// ------- Fused preprocessing: rmsnorm + w_qkv^T + w_out^T in ONE launch ----------
__device__ __forceinline__ void transpose_tile(const float* __restrict__ src,
                                               u16* __restrict__ dst,
                                               int R, int C, int r0, int c0, int tid,
                                               float* t /*[32][33]*/) {
  const int rr = tid >> 3, cc = (tid & 7) * 4;
  f4 v = *(const f4*)&src[(size_t)(r0 + rr) * C + c0 + cc];
  t[rr * 33 + cc] = v[0]; t[rr * 33 + cc + 1] = v[1];
  t[rr * 33 + cc + 2] = v[2]; t[rr * 33 + cc + 3] = v[3];
  __syncthreads();
  const int oc = tid >> 3, orr = (tid & 7) * 4;
  u16x4 o;
#pragma unroll
  for (int k = 0; k < 4; ++k) o[k] = f2bf(t[(orr + k) * 33 + oc]);
  *(u16x4*)&dst[(size_t)(c0 + oc) * R + r0 + orr] = o;
}

__global__ __launch_bounds__(256) void k_prep(const float* __restrict__ x,
                                              const float* __restrict__ wn,
                                              const float* __restrict__ wqkv,
                                              const float* __restrict__ wout,
                                              u16* __restrict__ normed,
                                              u16* __restrict__ wqkvT,
                                              u16* __restrict__ woutT) {
  __shared__ float t[32 * 33];
  const int bid = blockIdx.x, tid = threadIdx.x;
  if (bid < 4096) {
    const float* xr = x + (size_t)bid * 2048;
    f4 a = *(const f4*)&xr[tid * 8];
    f4 b = *(const f4*)&xr[tid * 8 + 4];
    float ss = a[0]*a[0]+a[1]*a[1]+a[2]*a[2]+a[3]*a[3]+b[0]*b[0]+b[1]*b[1]+b[2]*b[2]+b[3]*b[3];
#pragma unroll
    for (int off = 32; off > 0; off >>= 1) ss += __shfl_xor(ss, off);
    __shared__ float red[4];
    if ((tid & 63) == 0) red[tid >> 6] = ss;
    __syncthreads();
    ss = red[0] + red[1] + red[2] + red[3];
    const float sc = rsqrtf(ss * (1.0f / 2048.0f) + 1e-5f);
    f4 wa = *(const f4*)&wn[tid * 8];
    f4 wb = *(const f4*)&wn[tid * 8 + 4];
    u16x8 o;
#pragma unroll
    for (int i = 0; i < 4; ++i) o[i] = f2bf(a[i] * sc * wa[i]);
#pragma unroll
    for (int i = 0; i < 4; ++i) o[4 + i] = f2bf(b[i] * sc * wb[i]);
    *(u16x8*)&normed[(size_t)bid * 2048 + tid * 8] = o;
  } else if (bid < 16384) {
    const int i = bid - 4096;
    transpose_tile(wqkv, wqkvT, 2048, 6144, (i / 192) * 32, (i % 192) * 32, tid, t);
  } else {
    const int i = bid - 16384;
    transpose_tile(wout, woutT, 2048, 2048, (i >> 6) * 32, (i & 63) * 32, tid, t);
  }
}

// ------ GEMM1: 128x128, 4 waves, 32x32x16 MFMA, 2-phase + FUSED RoPE epilogue ----
// Same LDS bytes as the 16x16 version (16 b128 reads / K-tile / wave) but HALF the
// MFMA instructions (16 vs 32) and 129 vs 155 matrix cycles per K-tile.
// 32x32x16 layouts: A/B lane l holds row/col = l&31, k = (l>>5)*8 + e (16B contig);
// C/D: col = l&31, row = (r&3) + 8*(r>>2) + 4*(l>>5), r in [0,16).
__device__ __forceinline__ void stage128(const u16* __restrict__ A,
                                         const u16* __restrict__ Bt,
                                         int m0, int n0, int kt,
                                         u16* dA, u16* dB, int tid) {
#pragma unroll
  for (int p = 0; p < 4; ++p) {
    int c = p * 256 + tid;
    int row = c >> 3, ch = c & 7, gch = ch ^ (row & 7);
    gload16(&A[(size_t)(m0 + row) * 2048 + kt * 64 + gch * 8], &dA[c * 8]);
    gload16(&Bt[(size_t)(n0 + row) * 2048 + kt * 64 + gch * 8], &dB[c * 8]);
  }
}

__global__ __launch_bounds__(256) void k_gemm_qkv(
    const u16* __restrict__ A, const u16* __restrict__ Bt,
    float* __restrict__ outK, float* __restrict__ outV,
    u16* __restrict__ vtf, u16* __restrict__ qr, u16* __restrict__ kr,
    const float* __restrict__ cosb, const float* __restrict__ sinb) {
  constexpr int NT = 32;                       // K=2048 / BK=64
  __shared__ __align__(16) u16 sm[4][128 * 64];   // lA = sm[0..1], lB = sm[2..3]
  const int tid = threadIdx.x;
  const int lane = tid & 63;
  const int w = tid >> 6;
  const int wr = w >> 1, wc = w & 1;
  const int l31 = lane & 31, khalf = lane >> 5;
  const int m0 = blockIdx.y * 128, n0 = blockIdx.x * 128;
  f32x16 acc[2][2] = {};

  stage128(A, Bt, m0, n0, 0, sm[0], sm[2], tid);
  asm volatile("s_waitcnt vmcnt(0)" ::: "memory");
  __builtin_amdgcn_s_barrier();

  for (int kt = 0; kt < NT; ++kt) {
    const int cur = kt & 1;
    if (kt + 1 < NT)
      stage128(A, Bt, m0, n0, kt + 1, sm[cur ^ 1], sm[2 + (cur ^ 1)], tid);

#pragma unroll
    for (int ks = 0; ks < 4; ++ks) {           // 4 k-slices of 16
      const int kb = ks * 2 + khalf;           // 8B-chunk index 0..7
      bf16x8 af[2], bfr[2];
#pragma unroll
      for (int fm = 0; fm < 2; ++fm) {
        int row = wr * 64 + fm * 32 + l31;
        int chn = kb ^ (row & 7);
        af[fm] = *(const bf16x8*)&sm[cur][row * 64 + chn * 8];
      }
#pragma unroll
      for (int fn = 0; fn < 2; ++fn) {
        int row = wc * 64 + fn * 32 + l31;
        int chn = kb ^ (row & 7);
        bfr[fn] = *(const bf16x8*)&sm[2 + cur][row * 64 + chn * 8];
      }
      __builtin_amdgcn_s_setprio(1);
#pragma unroll
      for (int fm = 0; fm < 2; ++fm)
#pragma unroll
        for (int fn = 0; fn < 2; ++fn)
          acc[fm][fn] = mfma32(af[fm], bfr[fn], acc[fm][fn]);
      __builtin_amdgcn_s_setprio(0);
    }
    asm volatile("s_waitcnt vmcnt(0)" ::: "memory");
    __builtin_amdgcn_s_barrier();
  }

  // ---- epilogue (32x32 C layout) ----
  const int sec = n0 >> 11;           // 0=q, 1=k, 2=v
  const int h = (n0 & 2047) >> 7;
  const int b_ = m0 >> 11;            // block never crosses batch boundary
  const int sm0 = m0 & 2047;
  u16* tile = (u16*)sm;               // 128x128 bf16 overlay of sm[0..1]
#pragma unroll
  for (int fm = 0; fm < 2; ++fm)
#pragma unroll
    for (int fn = 0; fn < 2; ++fn) {
      const int d = wc * 64 + fn * 32 + l31;
#pragma unroll
      for (int q = 0; q < 4; ++q) {
        const int base = wr * 64 + fm * 32 + 8 * q + 4 * khalf;  // local s of row r&3==0
        if (sec == 2) {
          u16x4 vt;
#pragma unroll
          for (int j = 0; j < 4; ++j) {
            float val = acc[fm][fn][q * 4 + j];
            outV[((size_t)(b_ * 16 + h) * 2048 + (sm0 + base + j)) * 128 + d] = val;
            vt[j] = f2bf(val);
          }
          *(u16x4*)&vtf[((size_t)(b_ * 16 + h) * 128 + d) * 2048 + sm0 + base] = vt;
        } else {
#pragma unroll
          for (int j = 0; j < 4; ++j) {
            float val = acc[fm][fn][q * 4 + j];
            const int sl = base + j;
            if (sec == 1)
              outK[((size_t)(b_ * 16 + h) * 2048 + (sm0 + sl)) * 128 + d] = val;
            tile[sl * 128 + (d ^ ((sl & 15) << 1))] = f2bf(val);
          }
        }
      }
    }
  if (sec < 2) {
    __syncthreads();
    // RoPE pass: thread = d-column pair (dcol, dcol+64), 32 s-rows.
    // cos/sin symmetric in d (concat(ang,ang)): load only d<64 half.
    const float* cA = (sec == 0) ? cosb : cosb + 262144;
    const float* sA = (sec == 0) ? sinb : sinb + 262144;
    u16* dst = (sec == 0) ? qr : kr;
    const float scale = (sec == 0) ? 0.08838834764831845f : 1.0f;
    const int dcol = tid & 63;
    const int srow0 = (tid >> 6) * 32;
    u16* drow = dst + (size_t)(b_ * 16 + h) * 2048 * 128;
#pragma unroll 4
    for (int si = 0; si < 32; ++si) {
      const int sl = srow0 + si;
      const int sg = sm0 + sl;
      const int xw = (sl & 15) << 1;
      float cl = cA[(size_t)sg * 128 + dcol];
      float sl_ = sA[(size_t)sg * 128 + dcol];
      float lo = bf2f(tile[sl * 128 + (dcol ^ xw)]);
      float hi = bf2f(tile[sl * 128 + ((dcol ^ xw) + 64)]);
      drow[(size_t)sg * 128 + dcol]      = f2bf((cl * lo + sl_ * hi) * scale);
      drow[(size_t)sg * 128 + 64 + dcol] = f2bf((cl * hi + sl_ * lo) * scale);
    }
  }
}

// ------ GEMM2: 128x128, 8 WAVES (512 thr), 16x16 MFMA (R14 form) -----------------
__device__ __forceinline__ void stage128_512(const u16* __restrict__ A,
                                             const u16* __restrict__ Bt,
                                             int m0, int n0, int kt,
                                             u16* dA, u16* dB, int tid) {
#pragma unroll
  for (int p = 0; p < 2; ++p) {
    int c = p * 512 + tid;
    int row = c >> 3, ch = c & 7, gch = ch ^ (row & 7);
    gload16(&A[(size_t)(m0 + row) * 2048 + kt * 64 + gch * 8], &dA[c * 8]);
    gload16(&Bt[(size_t)(n0 + row) * 2048 + kt * 64 + gch * 8], &dB[c * 8]);
  }
}

__global__ __launch_bounds__(512) void k_gemm_out(
    const u16* __restrict__ A, const u16* __restrict__ Bt,
    const float* __restrict__ emb, float* __restrict__ out0) {
  constexpr int NT = 32;
  __shared__ __align__(16) u16 sm[4][128 * 64];
  const int tid = threadIdx.x;
  const int lane = tid & 63;
  const int w = tid >> 6;
  const int wr = w >> 2, wc = w & 3;           // 2M x 4N
  const int g = lane >> 4, c15 = lane & 15;
  const int m0 = blockIdx.y * 128, n0 = blockIdx.x * 128;
  f32x4 acc[4][2] = {};

  stage128_512(A, Bt, m0, n0, 0, sm[0], sm[2], tid);
  asm volatile("s_waitcnt vmcnt(0)" ::: "memory");
  __builtin_amdgcn_s_barrier();

  for (int kt = 0; kt < NT; ++kt) {
    const int cur = kt & 1;
    if (kt + 1 < NT)
      stage128_512(A, Bt, m0, n0, kt + 1, sm[cur ^ 1], sm[2 + (cur ^ 1)], tid);

#pragma unroll
    for (int ks = 0; ks < 2; ++ks) {
      bf16x8 af[4], bfr[2];
#pragma unroll
      for (int i = 0; i < 4; ++i) {
        int row = wr * 64 + i * 16 + c15;
        int chn = (ks * 4 + g) ^ (row & 7);
        af[i] = *(const bf16x8*)&sm[cur][row * 64 + chn * 8];
      }
#pragma unroll
      for (int j = 0; j < 2; ++j) {
        int row = wc * 32 + j * 16 + c15;
        int chn = (ks * 4 + g) ^ (row & 7);
        bfr[j] = *(const bf16x8*)&sm[2 + cur][row * 64 + chn * 8];
      }
      __builtin_amdgcn_s_setprio(1);
#pragma unroll
      for (int i = 0; i < 4; ++i)
#pragma unroll
        for (int j = 0; j < 2; ++j)
          acc[i][j] = mfma16(af[i], bfr[j], acc[i][j]);
      __builtin_amdgcn_s_setprio(0);
    }
    asm volatile("s_waitcnt vmcnt(0)" ::: "memory");
    __builtin_amdgcn_s_barrier();
  }

  const int rb = m0 + wr * 64 + g * 4;
  const int cb = wc * 32 + c15;
#pragma unroll
  for (int i = 0; i < 4; ++i)
#pragma unroll
    for (int j = 0; j < 2; ++j)
#pragma unroll
      for (int r = 0; r < 4; ++r) {
        int mm = rb + i * 16 + r;
        int nn = n0 + cb + j * 16;
        size_t o = (size_t)mm * 2048 + nn;
        out0[o] = acc[i][j][r] + emb[o];
      }
}

// ------- Flash attention: SWAPPED QK^T + static-max softmax + XCD affinity --------
__device__ __forceinline__ void stage_kv(const u16* kb, const u16* vb, int kv0,
                                         u16* dK, u16* dV, int tid) {
#pragma unroll
  for (int p = 0; p < 4; ++p) {
    int c = p * 256 + tid;
    { int row = c >> 4, ch = c & 15, gch = ch ^ (row & 7);
      gload16(&kb[(size_t)(kv0 + row) * 128 + gch * 8], &dK[c * 8]); }
    { int row = c >> 3, ch = c & 7, gch = ch ^ (row & 7);
      gload16(&vb[(size_t)row * 2048 + kv0 + gch * 8], &dV[c * 8]); }
  }
}

__global__ __launch_bounds__(256) void k_attn(const u16* __restrict__ q_rot,
                                              const u16* __restrict__ k_rot,
                                              const u16* __restrict__ v_t,
                                              u16* __restrict__ attn_o) {
  const int lin = blockIdx.y * gridDim.x + blockIdx.x;   // 512 blocks
  const int xcd = lin & 7, idx = lin >> 3;
  const int bh = xcd * 4 + (idx >> 4);
  const int jp = idx & 15;
  const int b = bh >> 4, h = bh & 15;
  const int tid = threadIdx.x, w = tid >> 6, lane = tid & 63;
  const int g = lane >> 4, c15 = lane & 15;
  __shared__ __align__(16) u16 lK[2][64 * 128];
  __shared__ __align__(16) u16 lV[2][128 * 64];
  __shared__ __align__(16) u16 lP[4][16 * 64];   // [q=16][kv=64], chunk-XOR swizzled

  const u16* qb = q_rot + (size_t)bh * 2048 * 128;
  const u16* kb = k_rot + (size_t)bh * 2048 * 128;
  const u16* vb = v_t + (size_t)bh * 128 * 2048;
  const float L2E = 1.442695040888963f;
  const float SHIFT = 11.541560327111707f;       // 8*log2(e)

  for (int halfp = 0; halfp < 2; ++halfp) {
    const int qt = halfp ? jp : 31 - jp;
    const int q0 = qt * 64;
    const int nt = qt + 1;

    bf16x8 qf[4];
    const int qrow = q0 + w * 16 + c15;          // this lane's q-row (swapped layout)
#pragma unroll
    for (int f = 0; f < 4; ++f)
      qf[f] = *(const bf16x8*)&qb[(size_t)qrow * 128 + f * 32 + g * 8];

    f32x4 O[8];
#pragma unroll
    for (int i = 0; i < 8; ++i) O[i] = {0.f, 0.f, 0.f, 0.f};
    float lsum = 0.0f;

    stage_kv(kb, vb, 0, &lK[0][0], &lV[0][0], tid);
    asm volatile("s_waitcnt vmcnt(0)" ::: "memory");
    __builtin_amdgcn_s_barrier();

    int cur = 0;
    for (int t = 0; t < nt; ++t) {
      if (t + 1 < nt)
        stage_kv(kb, vb, (t + 1) * 64, &lK[cur ^ 1][0], &lV[cur ^ 1][0], tid);

      const int kv0 = t * 64;
      f32x4 S[4];
#pragma unroll
      for (int n = 0; n < 4; ++n) S[n] = {0.f, 0.f, 0.f, 0.f};
      __builtin_amdgcn_s_setprio(1);
#pragma unroll
      for (int ks = 0; ks < 4; ++ks) {
#pragma unroll
        for (int n = 0; n < 4; ++n) {
          int row = n * 16 + c15;
          int chn = (ks * 4 + g) ^ (row & 7);
          bf16x8 kf = *(const bf16x8*)&lK[cur][row * 128 + chn * 8];
          S[n] = mfma16(kf, qf[ks], S[n]);       // SWAPPED: rows=kv, cols=q
        }
      }
      __builtin_amdgcn_s_setprio(0);

      if (t == nt - 1) {   // diagonal tile: causal mask (kv > q)
#pragma unroll
        for (int n = 0; n < 4; ++n)
#pragma unroll
          for (int r = 0; r < 4; ++r)
            if (kv0 + n * 16 + g * 4 + r > qrow) S[n][r] = -1e30f;
      }
#pragma unroll
      for (int n = 0; n < 4; ++n) {
        float p0 = exp2f(__builtin_fmaf(S[n][0], L2E, -SHIFT));
        float p1 = exp2f(__builtin_fmaf(S[n][1], L2E, -SHIFT));
        float p2 = exp2f(__builtin_fmaf(S[n][2], L2E, -SHIFT));
        float p3 = exp2f(__builtin_fmaf(S[n][3], L2E, -SHIFT));
        lsum += (p0 + p1) + (p2 + p3);
        u32x2 pw;
        pw[0] = (u32)f2bf(p0) | ((u32)f2bf(p1) << 16);
        pw[1] = (u32)f2bf(p2) | ((u32)f2bf(p3) << 16);
        int chunk = n * 2 + (g >> 1);
        int eoff = c15 * 64 + ((chunk ^ (c15 & 7)) << 3) + ((g & 1) << 2);
        *(u32x2*)&lP[w][eoff] = pw;
      }

      __builtin_amdgcn_s_setprio(1);
#pragma unroll
      for (int ks = 0; ks < 2; ++ks) {
        int ch2 = (ks * 4 + g) ^ (c15 & 7);
        bf16x8 pf = *(const bf16x8*)&lP[w][c15 * 64 + ch2 * 8];
#pragma unroll
        for (int nn = 0; nn < 8; ++nn) {
          int row = nn * 16 + c15;
          int chn = (ks * 4 + g) ^ (row & 7);
          bf16x8 vf = *(const bf16x8*)&lV[cur][row * 64 + chn * 8];
          O[nn] = mfma16(pf, vf, O[nn]);
        }
      }
      __builtin_amdgcn_s_setprio(0);

      asm volatile("s_waitcnt vmcnt(0)" ::: "memory");
      __builtin_amdgcn_s_barrier();
      cur ^= 1;
    }

    lsum += __shfl_xor(lsum, 16);
    lsum += __shfl_xor(lsum, 32);
    const float inv = 1.0f / lsum;               // for q = q0 + w*16 + c15
    float invr[4];
#pragma unroll
    for (int r = 0; r < 4; ++r)
      invr[r] = __shfl(inv, g * 4 + r);
#pragma unroll
    for (int nn = 0; nn < 8; ++nn)
#pragma unroll
      for (int r = 0; r < 4; ++r) {
        int s_ = q0 + w * 16 + g * 4 + r;
        int col = h * 128 + nn * 16 + c15;
        attn_o[(size_t)(b * 2048 + s_) * 2048 + col] = f2bf(O[nn][r] * invr[r]);
      }
  }
}

extern "C" void kernel_launch(void* const* d_in, const int* in_sizes, int n_in,
                              void* d_out, int out_size, void* d_ws, size_t ws_size,
                              hipStream_t stream) {
  const float* emb    = (const float*)d_in[0];
  const float* cosb   = (const float*)d_in[1];
  const float* sinb   = (const float*)d_in[2];
  const float* w_norm = (const float*)d_in[4];
  const float* w_qkv  = (const float*)d_in[5];
  const float* w_out  = (const float*)d_in[6];

  float* out0 = (float*)d_out;                 // (B,S,E) = 4096x2048
  float* outK = out0 + 8388608;                // present_k (B,H,S,K)
  float* outV = out0 + 16777216;               // present_v (B,H,S,V)

  char* ws = (char*)d_ws;
  u16* normed = (u16*)(ws + 0);
  u16* wqkvT  = (u16*)(ws + 16777216);
  u16* woutT  = (u16*)(ws + 41943040);
  u16* q_rot  = (u16*)(ws + 67108864);
  u16* k_rot  = (u16*)(ws + 83886080);
  u16* attn_o = normed;
  u16* v_t    = (u16*)(ws + 100663296);

  k_prep<<<20480, 256, 0, stream>>>(emb, w_norm, w_qkv, w_out, normed, wqkvT, woutT);
  k_gemm_qkv<<<dim3(48, 32), 256, 0, stream>>>(normed, wqkvT, outK, outV, v_t,
                                               q_rot, k_rot, cosb, sinb);
  k_attn<<<dim3(16, 32), 256, 0, stream>>>(q_rot, k_rot, v_t, attn_o);
  k_gemm_out<<<dim3(16, 32), 512, 0, stream>>>(attn_o, woutT, emb, out0);
}

// Round 16
// 262.658 us; speedup vs baseline: 1.0267x; 1.0267x over previous
//
#include <hip/hip_runtime.h>

typedef unsigned short u16;
typedef unsigned int   u32;
typedef short bf16x8 __attribute__((ext_vector_type(8)));
typedef float f32x4  __attribute__((ext_vector_type(4)));
typedef float f4     __attribute__((ext_vector_type(4)));
typedef u16   u16x4  __attribute__((ext_vector_type(4)));
typedef u16   u16x8  __attribute__((ext_vector_type(8)));
typedef u32   u32x2  __attribute__((ext_vector_type(2)));

__device__ __forceinline__ u16 f2bf(float x) {
  u32 u = __float_as_uint(x);
  u += 0x7fff + ((u >> 16) & 1);
  return (u16)(u >> 16);
}
__device__ __forceinline__ float bf2f(u16 h) {
  return __uint_as_float(((u32)h) << 16);
}
__device__ __forceinline__ void gload16(const void* g, void* l) {
  __builtin_amdgcn_global_load_lds((const __attribute__((address_space(1))) u32*)g,
                                   (__attribute__((address_space(3))) u32*)l, 16, 0, 0);
}
__device__ __forceinline__ f32x4 mfma16(bf16x8 a, bf16x8 b, f32x4 c) {
  return __builtin_amdgcn_mfma_f32_16x16x32_bf16(a, b, c, 0, 0, 0);
}

// ------- Fused preprocessing: rmsnorm + w_qkv^T + w_out^T in ONE launch ----------
__device__ __forceinline__ void transpose_tile(const float* __restrict__ src,
                                               u16* __restrict__ dst,
                                               int R, int C, int r0, int c0, int tid,
                                               float* t /*[32][33]*/) {
  const int rr = tid >> 3, cc = (tid & 7) * 4;
  f4 v = *(const f4*)&src[(size_t)(r0 + rr) * C + c0 + cc];
  t[rr * 33 + cc] = v[0]; t[rr * 33 + cc + 1] = v[1];
  t[rr * 33 + cc + 2] = v[2]; t[rr * 33 + cc + 3] = v[3];
  __syncthreads();
  const int oc = tid >> 3, orr = (tid & 7) * 4;
  u16x4 o;
#pragma unroll
  for (int k = 0; k < 4; ++k) o[k] = f2bf(t[(orr + k) * 33 + oc]);
  *(u16x4*)&dst[(size_t)(c0 + oc) * R + r0 + orr] = o;
}

__global__ __launch_bounds__(256) void k_prep(const float* __restrict__ x,
                                              const float* __restrict__ wn,
                                              const float* __restrict__ wqkv,
                                              const float* __restrict__ wout,
                                              u16* __restrict__ normed,
                                              u16* __restrict__ wqkvT,
                                              u16* __restrict__ woutT) {
  __shared__ float t[32 * 33];
  const int bid = blockIdx.x, tid = threadIdx.x;
  if (bid < 4096) {
    const float* xr = x + (size_t)bid * 2048;
    f4 a = *(const f4*)&xr[tid * 8];
    f4 b = *(const f4*)&xr[tid * 8 + 4];
    float ss = a[0]*a[0]+a[1]*a[1]+a[2]*a[2]+a[3]*a[3]+b[0]*b[0]+b[1]*b[1]+b[2]*b[2]+b[3]*b[3];
#pragma unroll
    for (int off = 32; off > 0; off >>= 1) ss += __shfl_xor(ss, off);
    __shared__ float red[4];
    if ((tid & 63) == 0) red[tid >> 6] = ss;
    __syncthreads();
    ss = red[0] + red[1] + red[2] + red[3];
    const float sc = rsqrtf(ss * (1.0f / 2048.0f) + 1e-5f);
    f4 wa = *(const f4*)&wn[tid * 8];
    f4 wb = *(const f4*)&wn[tid * 8 + 4];
    u16x8 o;
#pragma unroll
    for (int i = 0; i < 4; ++i) o[i] = f2bf(a[i] * sc * wa[i]);
#pragma unroll
    for (int i = 0; i < 4; ++i) o[4 + i] = f2bf(b[i] * sc * wb[i]);
    *(u16x8*)&normed[(size_t)bid * 2048 + tid * 8] = o;
  } else if (bid < 16384) {
    const int i = bid - 4096;
    transpose_tile(wqkv, wqkvT, 2048, 6144, (i / 192) * 32, (i % 192) * 32, tid, t);
  } else {
    const int i = bid - 16384;
    transpose_tile(wout, woutT, 2048, 2048, (i >> 6) * 32, (i & 63) * 32, tid, t);
  }
}

// ------ GEMM1: 128x128, 4 waves, T3-minimum 2-phase + FUSED RoPE epilogue --------
__device__ __forceinline__ void stage128(const u16* __restrict__ A,
                                         const u16* __restrict__ Bt,
                                         int m0, int n0, int kt,
                                         u16* dA, u16* dB, int tid) {
#pragma unroll
  for (int p = 0; p < 4; ++p) {
    int c = p * 256 + tid;
    int row = c >> 3, ch = c & 7, gch = ch ^ (row & 7);
    gload16(&A[(size_t)(m0 + row) * 2048 + kt * 64 + gch * 8], &dA[c * 8]);
    gload16(&Bt[(size_t)(n0 + row) * 2048 + kt * 64 + gch * 8], &dB[c * 8]);
  }
}

__global__ __launch_bounds__(256) void k_gemm_qkv(
    const u16* __restrict__ A, const u16* __restrict__ Bt,
    float* __restrict__ outK, float* __restrict__ outV,
    u16* __restrict__ vtf, u16* __restrict__ qr, u16* __restrict__ kr,
    const float* __restrict__ cosb, const float* __restrict__ sinb) {
  constexpr int NT = 32;                       // K=2048 / BK=64
  __shared__ __align__(16) u16 sm[4][128 * 64];   // lA = sm[0..1], lB = sm[2..3]
  const int tid = threadIdx.x;
  const int lane = tid & 63;
  const int w = tid >> 6;
  const int wr = w >> 1, wc = w & 1;
  const int g = lane >> 4, c15 = lane & 15;
  const int m0 = blockIdx.y * 128, n0 = blockIdx.x * 128;
  f32x4 acc[4][4] = {};

  stage128(A, Bt, m0, n0, 0, sm[0], sm[2], tid);
  asm volatile("s_waitcnt vmcnt(0)" ::: "memory");
  __builtin_amdgcn_s_barrier();

  for (int kt = 0; kt < NT; ++kt) {
    const int cur = kt & 1;
    if (kt + 1 < NT)
      stage128(A, Bt, m0, n0, kt + 1, sm[cur ^ 1], sm[2 + (cur ^ 1)], tid);

#pragma unroll
    for (int ks = 0; ks < 2; ++ks) {
      bf16x8 af[4], bfr[4];
#pragma unroll
      for (int i = 0; i < 4; ++i) {
        int row = wr * 64 + i * 16 + c15;
        int chn = (ks * 4 + g) ^ (row & 7);
        af[i] = *(const bf16x8*)&sm[cur][row * 64 + chn * 8];
      }
#pragma unroll
      for (int j = 0; j < 4; ++j) {
        int row = wc * 64 + j * 16 + c15;
        int chn = (ks * 4 + g) ^ (row & 7);
        bfr[j] = *(const bf16x8*)&sm[2 + cur][row * 64 + chn * 8];
      }
      __builtin_amdgcn_s_setprio(1);
#pragma unroll
      for (int i = 0; i < 4; ++i)
#pragma unroll
        for (int j = 0; j < 4; ++j)
          acc[i][j] = mfma16(af[i], bfr[j], acc[i][j]);
      __builtin_amdgcn_s_setprio(0);
    }
    asm volatile("s_waitcnt vmcnt(0)" ::: "memory");
    __builtin_amdgcn_s_barrier();
  }

  const int rb = m0 + wr * 64 + g * 4;
  const int cb = wc * 64 + c15;
  const int sec = n0 >> 11;           // 0=q, 1=k, 2=v
  const int h = (n0 & 2047) >> 7;
  u16* tile = (u16*)sm;               // 128x128 bf16 overlay of sm[0..1]
#pragma unroll
  for (int i = 0; i < 4; ++i)
#pragma unroll
    for (int j = 0; j < 4; ++j) {
      const int d = cb + j * 16;
      const int mb = rb + i * 16;
      const int b_ = mb >> 11, s0 = mb & 2047;
      if (sec == 2) {
        u16x4 vt;
#pragma unroll
        for (int r = 0; r < 4; ++r) {
          size_t o = ((size_t)(b_ * 16 + h) * 2048 + (s0 + r)) * 128 + d;
          outV[o] = acc[i][j][r];
          vt[r] = f2bf(acc[i][j][r]);
        }
        *(u16x4*)&vtf[((size_t)(b_ * 16 + h) * 128 + d) * 2048 + s0] = vt;
      } else {
#pragma unroll
        for (int r = 0; r < 4; ++r) {
          const int sl = wr * 64 + i * 16 + g * 4 + r;   // s_local = mb+r - m0
          if (sec == 1) {
            size_t o = ((size_t)(b_ * 16 + h) * 2048 + (s0 + r)) * 128 + d;
            outK[o] = acc[i][j][r];
          }
          tile[sl * 128 + (d ^ ((sl & 15) << 1))] = f2bf(acc[i][j][r]);
        }
      }
    }
  if (sec < 2) {
    __syncthreads();
    // RoPE pass: thread = d-column pair (dcol, dcol+64), 32 s-rows.
    // cos/sin symmetric in d (concat(ang,ang)): load only d<64 half.
    const float* cA = (sec == 0) ? cosb : cosb + 262144;
    const float* sA = (sec == 0) ? sinb : sinb + 262144;
    u16* dst = (sec == 0) ? qr : kr;
    const float scale = (sec == 0) ? 0.08838834764831845f : 1.0f;
    const int b_ = m0 >> 11;
    const int sbase = m0 & 2047;
    const int dcol = tid & 63;
    const int srow0 = (tid >> 6) * 32;
    u16* drow = dst + (size_t)(b_ * 16 + h) * 2048 * 128;
#pragma unroll 4
    for (int si = 0; si < 32; ++si) {
      const int sl = srow0 + si;
      const int sg = sbase + sl;
      const int xw = (sl & 15) << 1;
      float cl = cA[(size_t)sg * 128 + dcol];
      float sl_ = sA[(size_t)sg * 128 + dcol];
      float lo = bf2f(tile[sl * 128 + (dcol ^ xw)]);
      float hi = bf2f(tile[sl * 128 + ((dcol ^ xw) + 64)]);
      drow[(size_t)sg * 128 + dcol]      = f2bf((cl * lo + sl_ * hi) * scale);
      drow[(size_t)sg * 128 + 64 + dcol] = f2bf((cl * hi + sl_ * lo) * scale);
    }
  }
}

// ------ GEMM2: 128x128, 8 WAVES (512 thr) — 2 waves/SIMD intra-block TLP ---------
__device__ __forceinline__ void stage128_512(const u16* __restrict__ A,
                                             const u16* __restrict__ Bt,
                                             int m0, int n0, int kt,
                                             u16* dA, u16* dB, int tid) {
#pragma unroll
  for (int p = 0; p < 2; ++p) {
    int c = p * 512 + tid;
    int row = c >> 3, ch = c & 7, gch = ch ^ (row & 7);
    gload16(&A[(size_t)(m0 + row) * 2048 + kt * 64 + gch * 8], &dA[c * 8]);
    gload16(&Bt[(size_t)(n0 + row) * 2048 + kt * 64 + gch * 8], &dB[c * 8]);
  }
}

__global__ __launch_bounds__(512) void k_gemm_out(
    const u16* __restrict__ A, const u16* __restrict__ Bt,
    const float* __restrict__ emb, float* __restrict__ out0) {
  constexpr int NT = 32;
  __shared__ __align__(16) u16 sm[4][128 * 64];
  const int tid = threadIdx.x;
  const int lane = tid & 63;
  const int w = tid >> 6;
  const int wr = w >> 2, wc = w & 3;           // 2M x 4N
  const int g = lane >> 4, c15 = lane & 15;
  const int m0 = blockIdx.y * 128, n0 = blockIdx.x * 128;
  f32x4 acc[4][2] = {};

  stage128_512(A, Bt, m0, n0, 0, sm[0], sm[2], tid);
  asm volatile("s_waitcnt vmcnt(0)" ::: "memory");
  __builtin_amdgcn_s_barrier();

  for (int kt = 0; kt < NT; ++kt) {
    const int cur = kt & 1;
    if (kt + 1 < NT)
      stage128_512(A, Bt, m0, n0, kt + 1, sm[cur ^ 1], sm[2 + (cur ^ 1)], tid);

#pragma unroll
    for (int ks = 0; ks < 2; ++ks) {
      bf16x8 af[4], bfr[2];
#pragma unroll
      for (int i = 0; i < 4; ++i) {
        int row = wr * 64 + i * 16 + c15;
        int chn = (ks * 4 + g) ^ (row & 7);
        af[i] = *(const bf16x8*)&sm[cur][row * 64 + chn * 8];
      }
#pragma unroll
      for (int j = 0; j < 2; ++j) {
        int row = wc * 32 + j * 16 + c15;
        int chn = (ks * 4 + g) ^ (row & 7);
        bfr[j] = *(const bf16x8*)&sm[2 + cur][row * 64 + chn * 8];
      }
      __builtin_amdgcn_s_setprio(1);
#pragma unroll
      for (int i = 0; i < 4; ++i)
#pragma unroll
        for (int j = 0; j < 2; ++j)
          acc[i][j] = mfma16(af[i], bfr[j], acc[i][j]);
      __builtin_amdgcn_s_setprio(0);
    }
    asm volatile("s_waitcnt vmcnt(0)" ::: "memory");
    __builtin_amdgcn_s_barrier();
  }

  const int rb = m0 + wr * 64 + g * 4;
  const int cb = wc * 32 + c15;
#pragma unroll
  for (int i = 0; i < 4; ++i)
#pragma unroll
    for (int j = 0; j < 2; ++j)
#pragma unroll
      for (int r = 0; r < 4; ++r) {
        int mm = rb + i * 16 + r;
        int nn = n0 + cb + j * 16;
        size_t o = (size_t)mm * 2048 + nn;
        out0[o] = acc[i][j][r] + emb[o];
      }
}

// ------- Flash attention: SWAPPED QK^T + static-max softmax + XCD affinity --------
__device__ __forceinline__ void stage_kv(const u16* kb, const u16* vb, int kv0,
                                         u16* dK, u16* dV, int tid) {
#pragma unroll
  for (int p = 0; p < 4; ++p) {
    int c = p * 256 + tid;
    { int row = c >> 4, ch = c & 15, gch = ch ^ (row & 7);
      gload16(&kb[(size_t)(kv0 + row) * 128 + gch * 8], &dK[c * 8]); }
    { int row = c >> 3, ch = c & 7, gch = ch ^ (row & 7);
      gload16(&vb[(size_t)row * 2048 + kv0 + gch * 8], &dV[c * 8]); }
  }
}

__global__ __launch_bounds__(256) void k_attn(const u16* __restrict__ q_rot,
                                              const u16* __restrict__ k_rot,
                                              const u16* __restrict__ v_t,
                                              u16* __restrict__ attn_o) {
  const int lin = blockIdx.y * gridDim.x + blockIdx.x;   // 512 blocks
  const int xcd = lin & 7, idx = lin >> 3;
  const int bh = xcd * 4 + (idx >> 4);
  const int jp = idx & 15;
  const int b = bh >> 4, h = bh & 15;
  const int tid = threadIdx.x, w = tid >> 6, lane = tid & 63;
  const int g = lane >> 4, c15 = lane & 15;
  __shared__ __align__(16) u16 lK[2][64 * 128];
  __shared__ __align__(16) u16 lV[2][128 * 64];
  __shared__ __align__(16) u16 lP[4][16 * 64];   // [q=16][kv=64], chunk-XOR swizzled

  const u16* qb = q_rot + (size_t)bh * 2048 * 128;
  const u16* kb = k_rot + (size_t)bh * 2048 * 128;
  const u16* vb = v_t + (size_t)bh * 128 * 2048;
  const float L2E = 1.442695040888963f;
  const float SHIFT = 11.541560327111707f;       // 8*log2(e)

  for (int halfp = 0; halfp < 2; ++halfp) {
    const int qt = halfp ? jp : 31 - jp;
    const int q0 = qt * 64;
    const int nt = qt + 1;

    bf16x8 qf[4];
    const int qrow = q0 + w * 16 + c15;          // this lane's q-row (swapped layout)
#pragma unroll
    for (int f = 0; f < 4; ++f)
      qf[f] = *(const bf16x8*)&qb[(size_t)qrow * 128 + f * 32 + g * 8];

    f32x4 O[8];
#pragma unroll
    for (int i = 0; i < 8; ++i) O[i] = {0.f, 0.f, 0.f, 0.f};
    float lsum = 0.0f;

    stage_kv(kb, vb, 0, &lK[0][0], &lV[0][0], tid);
    asm volatile("s_waitcnt vmcnt(0)" ::: "memory");
    __builtin_amdgcn_s_barrier();

    int cur = 0;
    for (int t = 0; t < nt; ++t) {
      if (t + 1 < nt)
        stage_kv(kb, vb, (t + 1) * 64, &lK[cur ^ 1][0], &lV[cur ^ 1][0], tid);

      const int kv0 = t * 64;
      f32x4 S[4];
#pragma unroll
      for (int n = 0; n < 4; ++n) S[n] = {0.f, 0.f, 0.f, 0.f};
      __builtin_amdgcn_s_setprio(1);
#pragma unroll
      for (int ks = 0; ks < 4; ++ks) {
#pragma unroll
        for (int n = 0; n < 4; ++n) {
          int row = n * 16 + c15;
          int chn = (ks * 4 + g) ^ (row & 7);
          bf16x8 kf = *(const bf16x8*)&lK[cur][row * 128 + chn * 8];
          S[n] = mfma16(kf, qf[ks], S[n]);       // SWAPPED: rows=kv, cols=q
        }
      }
      __builtin_amdgcn_s_setprio(0);

      if (t == nt - 1) {   // diagonal tile: causal mask (kv > q)
#pragma unroll
        for (int n = 0; n < 4; ++n)
#pragma unroll
          for (int r = 0; r < 4; ++r)
            if (kv0 + n * 16 + g * 4 + r > qrow) S[n][r] = -1e30f;
      }
#pragma unroll
      for (int n = 0; n < 4; ++n) {
        float p0 = exp2f(__builtin_fmaf(S[n][0], L2E, -SHIFT));
        float p1 = exp2f(__builtin_fmaf(S[n][1], L2E, -SHIFT));
        float p2 = exp2f(__builtin_fmaf(S[n][2], L2E, -SHIFT));
        float p3 = exp2f(__builtin_fmaf(S[n][3], L2E, -SHIFT));
        lsum += (p0 + p1) + (p2 + p3);
        u32x2 pw;
        pw[0] = (u32)f2bf(p0) | ((u32)f2bf(p1) << 16);
        pw[1] = (u32)f2bf(p2) | ((u32)f2bf(p3) << 16);
        int chunk = n * 2 + (g >> 1);
        int eoff = c15 * 64 + ((chunk ^ (c15 & 7)) << 3) + ((g & 1) << 2);
        *(u32x2*)&lP[w][eoff] = pw;
      }

      __builtin_amdgcn_s_setprio(1);
#pragma unroll
      for (int ks = 0; ks < 2; ++ks) {
        int ch2 = (ks * 4 + g) ^ (c15 & 7);
        bf16x8 pf = *(const bf16x8*)&lP[w][c15 * 64 + ch2 * 8];
#pragma unroll
        for (int nn = 0; nn < 8; ++nn) {
          int row = nn * 16 + c15;
          int chn = (ks * 4 + g) ^ (row & 7);
          bf16x8 vf = *(const bf16x8*)&lV[cur][row * 64 + chn * 8];
          O[nn] = mfma16(pf, vf, O[nn]);
        }
      }
      __builtin_amdgcn_s_setprio(0);

      asm volatile("s_waitcnt vmcnt(0)" ::: "memory");
      __builtin_amdgcn_s_barrier();
      cur ^= 1;
    }

    lsum += __shfl_xor(lsum, 16);
    lsum += __shfl_xor(lsum, 32);
    const float inv = 1.0f / lsum;               // for q = q0 + w*16 + c15
    float invr[4];
#pragma unroll
    for (int r = 0; r < 4; ++r)
      invr[r] = __shfl(inv, g * 4 + r);
#pragma unroll
    for (int nn = 0; nn < 8; ++nn)
#pragma unroll
      for (int r = 0; r < 4; ++r) {
        int s_ = q0 + w * 16 + g * 4 + r;
        int col = h * 128 + nn * 16 + c15;
        attn_o[(size_t)(b * 2048 + s_) * 2048 + col] = f2bf(O[nn][r] * invr[r]);
      }
  }
}

extern "C" void kernel_launch(void* const* d_in, const int* in_sizes, int n_in,
                              void* d_out, int out_size, void* d_ws, size_t ws_size,
                              hipStream_t stream) {
  const float* emb    = (const float*)d_in[0];
  const float* cosb   = (const float*)d_in[1];
  const float* sinb   = (const float*)d_in[2];
  const float* w_norm = (const float*)d_in[4];
  const float* w_qkv  = (const float*)d_in[5];
  const float* w_out  = (const float*)d_in[6];

  float* out0 = (float*)d_out;                 // (B,S,E) = 4096x2048
  float* outK = out0 + 8388608;                // present_k (B,H,S,K)
  float* outV = out0 + 16777216;               // present_v (B,H,S,V)

  char* ws = (char*)d_ws;
  u16* normed = (u16*)(ws + 0);
  u16* wqkvT  = (u16*)(ws + 16777216);
  u16* woutT  = (u16*)(ws + 41943040);
  u16* q_rot  = (u16*)(ws + 67108864);
  u16* k_rot  = (u16*)(ws + 83886080);
  u16* attn_o = normed;
  u16* v_t    = (u16*)(ws + 100663296);

  k_prep<<<20480, 256, 0, stream>>>(emb, w_norm, w_qkv, w_out, normed, wqkvT, woutT);
  k_gemm_qkv<<<dim3(48, 32), 256, 0, stream>>>(normed, wqkvT, outK, outV, v_t,
                                               q_rot, k_rot, cosb, sinb);
  k_attn<<<dim3(16, 32), 256, 0, stream>>>(q_rot, k_rot, v_t, attn_o);
  k_gemm_out<<<dim3(16, 32), 512, 0, stream>>>(attn_o, woutT, emb, out0);
}